// Round 1
// baseline (767.861 us; speedup 1.0000x reference)
//
#include <hip/hip_runtime.h>
#include <stdint.h>

// ---------------- types / helpers ----------------
typedef unsigned short bfu;                                  // bf16 bits
typedef float  f32x4  __attribute__((ext_vector_type(4)));
typedef short  bf16x8 __attribute__((ext_vector_type(8)));

#define LAMBDA_INIT_F   0.777870099559256f
#define ONE_MINUS_LI_F  0.222129900440744f

__device__ __forceinline__ unsigned short f2bf(float f) {
    unsigned int u = __float_as_uint(f);
    u += 0x7fffu + ((u >> 16) & 1u);   // RNE
    return (unsigned short)(u >> 16);
}

// ---------------- 1) convert all f32 inputs -> packed bf16 region ----------------
// dst layout (elements): x[4194304] wq1[1048576] wq2 wk1 wk2 wv[2097152] wc[2097152]
__global__ void cvt_all(const float* __restrict__ s0, const float* __restrict__ s1,
                        const float* __restrict__ s2, const float* __restrict__ s3,
                        const float* __restrict__ s4, const float* __restrict__ s5,
                        const float* __restrict__ s6, bfu* __restrict__ dst)
{
    const int total = 3145728;                 // float4 chunks
    int i = blockIdx.x * 256 + threadIdx.x;
    const int stride = gridDim.x * 256;
    for (; i < total; i += stride) {
        const float* s; int off;
        if      (i < 1048576) { s = s0; off = i; }
        else if (i < 1310720) { s = s1; off = i - 1048576; }
        else if (i < 1572864) { s = s2; off = i - 1310720; }
        else if (i < 1835008) { s = s3; off = i - 1572864; }
        else if (i < 2097152) { s = s4; off = i - 1835008; }
        else if (i < 2621440) { s = s5; off = i - 2097152; }
        else                  { s = s6; off = i - 2621440; }
        float4 vv = ((const float4*)s)[off];
        ushort4 o;
        o.x = f2bf(vv.x); o.y = f2bf(vv.y); o.z = f2bf(vv.z); o.w = f2bf(vv.w);
        ((ushort4*)dst)[i] = o;
    }
}

// ---------------- 2) bt-GEMM (C = A * B^T), 128x128 tile, BK=32, 4 waves ----------------
// OUTMODE 0: fused QKV projection epilogue (bf16, head layouts, N=6144)
// OUTMODE 1: plain f32 row-major [4096][1024] epilogue
template <int OUTMODE>
__global__ __launch_bounds__(256, 2) void gemm_bt(
    const bfu* __restrict__ A, const bfu* __restrict__ Bw,
    void* __restrict__ outp, const int K)
{
    // +8 element row padding -> 80B rows: kills the 64B-stride bank conflicts
    __shared__ __attribute__((aligned(16))) bfu As[128 * 40];
    __shared__ __attribute__((aligned(16))) bfu Bs[128 * 40];

    const int tid  = threadIdx.x;
    const int lane = tid & 63;
    const int w    = tid >> 6;
    const int lr   = lane >> 4, lc = lane & 15;
    const int wr   = w >> 1,    wc = w & 1;
    const int m0   = blockIdx.y << 7;
    const int n0   = blockIdx.x << 7;

    const f32x4 zero4 = {0.f, 0.f, 0.f, 0.f};
    f32x4 acc[4][4];
#pragma unroll
    for (int i = 0; i < 4; ++i)
#pragma unroll
        for (int j = 0; j < 4; ++j) acc[i][j] = zero4;

    const bfu* Ag = A  + (size_t)m0 * K;
    const bfu* Bg = Bw + (size_t)n0 * K;

    for (int k0 = 0; k0 < K; k0 += 32) {
        __syncthreads();
#pragma unroll
        for (int j = 0; j < 2; ++j) {           // 512 16B chunks, 2 per thread
            const int cc  = j * 256 + tid;
            const int row = cc >> 2, kc = cc & 3;
            *(uint4*)(&As[row * 40 + kc * 8]) = *(const uint4*)(Ag + (size_t)row * K + k0 + kc * 8);
            *(uint4*)(&Bs[row * 40 + kc * 8]) = *(const uint4*)(Bg + (size_t)row * K + k0 + kc * 8);
        }
        __syncthreads();
        bf16x8 af[4], bfr[4];
#pragma unroll
        for (int mi = 0; mi < 4; ++mi)
            af[mi] = *(const bf16x8*)(&As[(wr * 64 + mi * 16 + lc) * 40 + lr * 8]);
#pragma unroll
        for (int ni = 0; ni < 4; ++ni)
            bfr[ni] = *(const bf16x8*)(&Bs[(wc * 64 + ni * 16 + lc) * 40 + lr * 8]);
#pragma unroll
        for (int mi = 0; mi < 4; ++mi)
#pragma unroll
            for (int ni = 0; ni < 4; ++ni)
                acc[mi][ni] = __builtin_amdgcn_mfma_f32_16x16x32_bf16(af[mi], bfr[ni], acc[mi][ni], 0, 0, 0);
    }

    // epilogue. D layout: row=(lane>>4)*4+r, col=lane&15
#pragma unroll
    for (int mi = 0; mi < 4; ++mi) {
#pragma unroll
        for (int ni = 0; ni < 4; ++ni) {
#pragma unroll
            for (int r = 0; r < 4; ++r) {
                const int m = m0 + wr * 64 + mi * 16 + lr * 4 + r;
                const int n = n0 + wc * 64 + ni * 16 + lc;
                const float val = acc[mi][ni][r];
                if (OUTMODE == 0) {
                    bfu* out = (bfu*)outp;
                    const int b = m >> 11, t = m & 2047;
                    size_t idx;
                    if (n < 4096) {            // q1,q2,k1,k2 : [B,H,T,64] each
                        const int mat = n >> 10, nn = n & 1023;
                        const int hh = nn >> 6, dd = nn & 63;
                        idx = (size_t)mat * 4194304 + ((((size_t)b * 16 + hh) * 2048 + t) << 6) + dd;
                    } else {                   // v : [B,H,T,128]
                        const int nn = n - 4096;
                        const int hh = nn >> 7, dd = nn & 127;
                        idx = (size_t)4 * 4194304 + ((((size_t)b * 16 + hh) * 2048 + t) << 7) + dd;
                    }
                    out[idx] = f2bf(val);
                } else {
                    float* out = (float*)outp;
                    out[(size_t)m * 1024 + n] = val;
                }
            }
        }
    }
}

// ---------------- 3) differential flash attention ----------------
// grid: (T/64, B*H). 4 waves, each wave owns 16 q-rows. KV tiles of 32.
__global__ __launch_bounds__(256, 2) void diff_attn(
    const bfu* __restrict__ q1g, const bfu* __restrict__ q2g,
    const bfu* __restrict__ k1g, const bfu* __restrict__ k2g,
    const bfu* __restrict__ vg,  float* __restrict__ y,
    const float* __restrict__ lq1, const float* __restrict__ lk1,
    const float* __restrict__ lq2, const float* __restrict__ lk2)
{
    __shared__ __attribute__((aligned(16))) bfu K1s[32 * 72];   // [32][64] + pad 8
    __shared__ __attribute__((aligned(16))) bfu K2s[32 * 72];
    __shared__ __attribute__((aligned(16))) bfu Vt[128 * 40];   // V^T: [128 d][32 t] + pad 8
    __shared__ __attribute__((aligned(16))) bfu P1s[4][16 * 40];
    __shared__ __attribute__((aligned(16))) bfu P2s[4][16 * 40];

    const int tid  = threadIdx.x;
    const int lane = tid & 63;
    const int w    = tid >> 6;
    const int lr   = lane >> 4, lc = lane & 15;
    const int bh   = blockIdx.y;
    const int h    = bh & 15;
    const int q0   = blockIdx.x << 6;

    const size_t bqk = (size_t)bh * (2048 * 64);
    const size_t bv  = (size_t)bh * (2048 * 128);

    // Q fragments (A operand: row = lane&15, k = (lane>>4)*8+j)
    const int qrow = q0 + w * 16 + lc;
    bf16x8 q1f[2], q2f[2];
#pragma unroll
    for (int c2 = 0; c2 < 2; ++c2) {
        q1f[c2] = *(const bf16x8*)(q1g + bqk + (size_t)qrow * 64 + c2 * 32 + lr * 8);
        q2f[c2] = *(const bf16x8*)(q2g + bqk + (size_t)qrow * 64 + c2 * 32 + lr * 8);
    }

    const f32x4 zero4 = {0.f, 0.f, 0.f, 0.f};
    f32x4 acc1[8], acc2[8];
    float m1[4], m2[4], l1[4], l2[4];
#pragma unroll
    for (int i = 0; i < 8; ++i) { acc1[i] = zero4; acc2[i] = zero4; }
#pragma unroll
    for (int r = 0; r < 4; ++r) { m1[r] = -1e30f; m2[r] = -1e30f; l1[r] = 0.f; l2[r] = 0.f; }

    const int myhi = q0 + w * 16 + 15;

    for (int kv0 = 0; kv0 < q0 + 64; kv0 += 32) {
        __syncthreads();
        {   // stage K1,K2 tiles [32][64]
            const int row = tid >> 3, dc = tid & 7;
            const size_t gsrc = bqk + (size_t)(kv0 + row) * 64 + dc * 8;
            *(uint4*)(&K1s[row * 72 + dc * 8]) = *(const uint4*)(k1g + gsrc);
            *(uint4*)(&K2s[row * 72 + dc * 8]) = *(const uint4*)(k2g + gsrc);
        }
#pragma unroll
        for (int j = 0; j < 2; ++j) {   // stage V transposed: Vt[d][t]
            const int cc = j * 256 + tid;
            const int row = cc >> 4, dc = cc & 15;
            uint4 raw = *(const uint4*)(vg + bv + (size_t)(kv0 + row) * 128 + dc * 8);
            unsigned short tmp[8];
            *(uint4*)tmp = raw;
#pragma unroll
            for (int jj = 0; jj < 8; ++jj) Vt[(dc * 8 + jj) * 40 + row] = tmp[jj];
        }
        __syncthreads();

        if (kv0 <= myhi) {
            // S = Q K^T   (B operand: col = lane&15 -> kv index, k = d)
            f32x4 s1[2], s2[2];
#pragma unroll
            for (int nb = 0; nb < 2; ++nb) {
                const int krow = nb * 16 + lc;
                bf16x8 kf10 = *(const bf16x8*)(&K1s[krow * 72 + lr * 8]);
                bf16x8 kf11 = *(const bf16x8*)(&K1s[krow * 72 + 32 + lr * 8]);
                bf16x8 kf20 = *(const bf16x8*)(&K2s[krow * 72 + lr * 8]);
                bf16x8 kf21 = *(const bf16x8*)(&K2s[krow * 72 + 32 + lr * 8]);
                s1[nb] = __builtin_amdgcn_mfma_f32_16x16x32_bf16(q1f[0], kf10, zero4, 0, 0, 0);
                s1[nb] = __builtin_amdgcn_mfma_f32_16x16x32_bf16(q1f[1], kf11, s1[nb], 0, 0, 0);
                s2[nb] = __builtin_amdgcn_mfma_f32_16x16x32_bf16(q2f[0], kf20, zero4, 0, 0, 0);
                s2[nb] = __builtin_amdgcn_mfma_f32_16x16x32_bf16(q2f[1], kf21, s2[nb], 0, 0, 0);
            }
            // scale + causal mask + row-max (rows live in 16-lane groups)
            float rmax1[4], rmax2[4];
#pragma unroll
            for (int r = 0; r < 4; ++r) {
                const int grow = q0 + w * 16 + lr * 4 + r;
                const int gcol = kv0 + lc;
                float a0 = (gcol      <= grow) ? s1[0][r] * 0.125f : -1e30f;
                float a1 = (gcol + 16 <= grow) ? s1[1][r] * 0.125f : -1e30f;
                float b0 = (gcol      <= grow) ? s2[0][r] * 0.125f : -1e30f;
                float b1 = (gcol + 16 <= grow) ? s2[1][r] * 0.125f : -1e30f;
                s1[0][r] = a0; s1[1][r] = a1; s2[0][r] = b0; s2[1][r] = b1;
                float a = fmaxf(a0, a1), b = fmaxf(b0, b1);
#pragma unroll
                for (int off = 1; off < 16; off <<= 1) {
                    a = fmaxf(a, __shfl_xor(a, off));
                    b = fmaxf(b, __shfl_xor(b, off));
                }
                rmax1[r] = a; rmax2[r] = b;
            }
            // online softmax update (independent states for att1 / att2)
            float c1[4], c2[4];
#pragma unroll
            for (int r = 0; r < 4; ++r) {
                const float nm1 = fmaxf(m1[r], rmax1[r]);
                const float nm2 = fmaxf(m2[r], rmax2[r]);
                c1[r] = __expf(m1[r] - nm1); m1[r] = nm1;
                c2[r] = __expf(m2[r] - nm2); m2[r] = nm2;
                const float p10 = __expf(s1[0][r] - nm1), p11 = __expf(s1[1][r] - nm1);
                const float p20 = __expf(s2[0][r] - nm2), p21 = __expf(s2[1][r] - nm2);
                const int prow = lr * 4 + r;
                P1s[w][prow * 40 + lc]      = f2bf(p10);
                P1s[w][prow * 40 + 16 + lc] = f2bf(p11);
                P2s[w][prow * 40 + lc]      = f2bf(p20);
                P2s[w][prow * 40 + 16 + lc] = f2bf(p21);
                float sa = p10 + p11, sb = p20 + p21;
#pragma unroll
                for (int off = 1; off < 16; off <<= 1) {
                    sa += __shfl_xor(sa, off);
                    sb += __shfl_xor(sb, off);
                }
                l1[r] = l1[r] * c1[r] + sa;
                l2[r] = l2[r] * c2[r] + sb;
            }
#pragma unroll
            for (int d8 = 0; d8 < 8; ++d8)
#pragma unroll
                for (int r = 0; r < 4; ++r) { acc1[d8][r] *= c1[r]; acc2[d8][r] *= c2[r]; }

            // PV: A = P (via per-wave LDS transpose), B = V (cols = d via Vt)
            bf16x8 p1f = *(const bf16x8*)(&P1s[w][lc * 40 + lr * 8]);
            bf16x8 p2f = *(const bf16x8*)(&P2s[w][lc * 40 + lr * 8]);
#pragma unroll
            for (int d8 = 0; d8 < 8; ++d8) {
                bf16x8 vf = *(const bf16x8*)(&Vt[(d8 * 16 + lc) * 40 + lr * 8]);
                acc1[d8] = __builtin_amdgcn_mfma_f32_16x16x32_bf16(p1f, vf, acc1[d8], 0, 0, 0);
                acc2[d8] = __builtin_amdgcn_mfma_f32_16x16x32_bf16(p2f, vf, acc2[d8], 0, 0, 0);
            }
        }
    }

    // epilogue: y = acc1/l1 - lam*acc2/l2
    float lam;
    {
        const float a = lq1[h] * lk1[h];
        const float b = lq2[h] * lk2[h];
        lam = 1.f / (1.f + __expf(-a)) - 1.f / (1.f + __expf(-b)) + LAMBDA_INIT_F;
    }
#pragma unroll
    for (int r = 0; r < 4; ++r) {
        const int grow = q0 + w * 16 + lr * 4 + r;
        const float inv1 = 1.f / l1[r], inv2 = 1.f / l2[r];
        float* dst = y + bv + (size_t)grow * 128;
#pragma unroll
        for (int d8 = 0; d8 < 8; ++d8)
            dst[d8 * 16 + lc] = acc1[d8][r] * inv1 - lam * acc2[d8][r] * inv2;
    }
}

// ---------------- 4) GroupNorm per (b,h,g) over (T x 4 channels) ----------------
// grid: B*H*G = 1024 blocks. Writes y2 bf16 in [B,T,2C] layout.
__global__ __launch_bounds__(256) void groupnorm_kernel(
    const float* __restrict__ yin, const float* __restrict__ gn_w,
    const float* __restrict__ gn_b, const float* __restrict__ gamma,
    bfu* __restrict__ y2)
{
    const int blk = blockIdx.x;
    const int g = blk & 31;
    const int h = (blk >> 5) & 15;
    const int b = blk >> 9;
    const int c0 = g << 2;
    const float* src = yin + ((size_t)(b * 16 + h)) * 262144 + c0;
    const int tid = threadIdx.x;

    float s = 0.f, ss = 0.f;
    for (int t = tid; t < 2048; t += 256) {
        float4 vv = *(const float4*)(src + (size_t)t * 128);
        s  += vv.x + vv.y + vv.z + vv.w;
        ss += vv.x * vv.x + vv.y * vv.y + vv.z * vv.z + vv.w * vv.w;
    }
#pragma unroll
    for (int off = 1; off < 64; off <<= 1) { s += __shfl_xor(s, off); ss += __shfl_xor(ss, off); }
    __shared__ float rs[4], rss[4];
    if ((tid & 63) == 0) { rs[tid >> 6] = s; rss[tid >> 6] = ss; }
    __syncthreads();
    const float S  = rs[0] + rs[1] + rs[2] + rs[3];
    const float SS = rss[0] + rss[1] + rss[2] + rss[3];
    const float mean = S * (1.f / 8192.f);
    const float var  = SS * (1.f / 8192.f) - mean * mean;
    const float rstd = rsqrtf(var + 1e-5f);

    float wv[4], bvv[4];
#pragma unroll
    for (int j = 0; j < 4; ++j) {
        const float gwj = gn_w[c0 + j] * gamma[c0 + j] * ONE_MINUS_LI_F;
        wv[j]  = gwj * rstd;
        bvv[j] = gn_b[c0 + j] * gamma[c0 + j] * ONE_MINUS_LI_F - mean * gwj * rstd;
    }
    bfu* dst = y2 + (size_t)b * 4194304 + (h << 7) + c0;
    for (int t = tid; t < 2048; t += 256) {
        float4 vv = *(const float4*)(src + (size_t)t * 128);
        ushort4 o;
        o.x = f2bf(vv.x * wv[0] + bvv[0]);
        o.y = f2bf(vv.y * wv[1] + bvv[1]);
        o.z = f2bf(vv.z * wv[2] + bvv[2]);
        o.w = f2bf(vv.w * wv[3] + bvv[3]);
        *(ushort4*)(dst + (size_t)t * 2048) = o;
    }
}

// ---------------- launch ----------------
extern "C" void kernel_launch(void* const* d_in, const int* in_sizes, int n_in,
                              void* d_out, int out_size, void* d_ws, size_t ws_size,
                              hipStream_t stream) {
    const float* x    = (const float*)d_in[0];
    const float* Wq1  = (const float*)d_in[1];
    const float* Wq2  = (const float*)d_in[2];
    const float* Wk1  = (const float*)d_in[3];
    const float* Wk2  = (const float*)d_in[4];
    const float* Wv   = (const float*)d_in[5];
    const float* Wc   = (const float*)d_in[6];
    const float* gn_w = (const float*)d_in[7];
    const float* gn_b = (const float*)d_in[8];
    const float* gm   = (const float*)d_in[9];
    const float* lq1  = (const float*)d_in[10];
    const float* lk1  = (const float*)d_in[11];
    const float* lq2  = (const float*)d_in[12];
    const float* lk2  = (const float*)d_in[13];

    // ws layout (elements of bfu unless noted)
    bfu* x_bf  = (bfu*)d_ws;                  // 4,194,304
    bfu* wgt   = x_bf + 4194304;              // 6,291,456  (wq1,wq2,wk1,wk2,wv packed)
    bfu* wc_bf = wgt + 6291456;               // 2,097,152
    bfu* q1    = wc_bf + 2097152;             // q1,q2,k1,k2: 4x4,194,304 ; v: 8,388,608
    bfu* vbuf  = q1 + 4 * 4194304;
    float* y_att = (float*)(q1 + 25165824);   // 8,388,608 f32
    bfu* y2    = (bfu*)(y_att + 8388608);     // 8,388,608

    cvt_all<<<2048, 256, 0, stream>>>(x, Wq1, Wq2, Wk1, Wk2, Wv, Wc, x_bf);

    gemm_bt<0><<<dim3(48, 32), 256, 0, stream>>>(x_bf, wgt, (void*)q1, 1024);

    diff_attn<<<dim3(32, 32), 256, 0, stream>>>(q1, q1 + 4194304, q1 + 2 * 4194304,
                                                q1 + 3 * 4194304, vbuf, y_att,
                                                lq1, lk1, lq2, lk2);

    groupnorm_kernel<<<1024, 256, 0, stream>>>(y_att, gn_w, gn_b, gm, y2);

    gemm_bt<1><<<dim3(8, 32), 256, 0, stream>>>(y2, wc_bf, d_out, 2048);
}